// Round 13
// baseline (109.892 us; speedup 1.0000x reference)
//
#include <hip/hip_runtime.h>

// Problem constants (from reference)
constexpr int C   = 4096;   // HIDDEN_DIM
constexpr int NE  = 4;      // EXPANSION
constexpr int B   = 4096;   // batch rows
constexpr int THREADS = 128;         // 2 waves per block, ONE ROW PER BLOCK
constexpr int NV = C / (THREADS*4);  // 8 float4 chunks per thread per stream
constexpr float EPSV = 1e-5f;

// Manual RNE round-to-bf16-and-back (value-based)
__device__ inline float bf16_rne(float f) {
    unsigned int u = __float_as_uint(f);
    unsigned int r = (u + 0x7FFFu + ((u >> 16) & 1u)) & 0xFFFF0000u;
    return __uint_as_float(r);
}

__device__ __forceinline__ void ld4(const float* __restrict__ p, float (&d)[4]) {
    float4 t = *reinterpret_cast<const float4*>(p);
    d[0] = t.x; d[1] = t.y; d[2] = t.z; d[3] = t.w;
}

// One row per 2-wave block. x held entirely in registers (128 VGPR),
// ONE barrier per row (only the 2-value ss exchange + sM publish), stores
// drain at kernel end — never at a barrier. 4096 independent blocks give
// chip-wide read/write mixing like the copy microbenchmark.
__global__ __launch_bounds__(THREADS)
void mhc_row(const float* __restrict__ x,
             const float* __restrict__ w,   // rmsnorm_weight stored as f32 on device
             const float* __restrict__ Hpre,
             const float* __restrict__ Hpost,
             const float* __restrict__ Hres,
             float* __restrict__ out) {
    const int tid  = threadIdx.x;
    const int lane = tid & 63;
    const int wid  = tid >> 6;
    const float* xrow = x   + (size_t)blockIdx.x * NE * C;
    float*       orow = out + (size_t)blockIdx.x * NE * C;

    // ---- issue ALL x loads first: 4 streams x 8 dense float4 chunks ----
    // chunk v, thread t -> cols [v*512 + t*4, +4): every instruction is a
    // fully dense 1 KB wave access.
    float xs[NE][NV][4];
    #pragma unroll
    for (int k = 0; k < NE; ++k)
        #pragma unroll
        for (int v = 0; v < NV; ++v)
            ld4(xrow + k * C + v * (THREADS * 4) + tid * 4, xs[k][v]);

    __shared__ float sM[NE * NE];
    __shared__ float sred[2];

    // ---- wave 0: lane-parallel Sinkhorn (butterfly), under the load shadow ----
    if (tid < 64) {
        float m = (tid < 16) ? expf(Hres[tid]) : 0.0f;
        for (int it = 0; it < 20; ++it) {
            float r = m + __shfl_xor(m, 1);
            r += __shfl_xor(r, 2);
            m /= fmaxf(r, EPSV);
            float cs = m + __shfl_xor(m, 4);
            cs += __shfl_xor(cs, 8);
            m /= fmaxf(cs, EPSV);
        }
        if (tid < 16) sM[tid] = m;
    }

    // ---- gates (uniform, cheap, per-thread) ----
    const float s0 = 1.0f / (1.0f + expf(-Hpre[0]));
    const float s1 = 1.0f / (1.0f + expf(-Hpre[1]));
    const float s2 = 1.0f / (1.0f + expf(-Hpre[2]));
    const float s3 = 1.0f / (1.0f + expf(-Hpre[3]));
    float hp[NE];
    #pragma unroll
    for (int i = 0; i < NE; ++i) hp[i] = 2.0f / (1.0f + expf(-Hpost[i]));

    // ---- per-lane sum of squares of bf16-rounded aggregate ----
    float ss = 0.0f;
    #pragma unroll
    for (int v = 0; v < NV; ++v)
        #pragma unroll
        for (int e = 0; e < 4; ++e) {
            float a = s0 * xs[0][v][e] + s1 * xs[1][v][e]
                    + s2 * xs[2][v][e] + s3 * xs[3][v][e];
            float abf = bf16_rne(a);
            ss += abf * abf;
        }

    // ---- wave butterfly + single 2-wave exchange (THE one barrier) ----
    #pragma unroll
    for (int off = 32; off > 0; off >>= 1) ss += __shfl_xor(ss, off);
    if (lane == 0) sred[wid] = ss;
    __syncthreads();                        // also publishes sM
    const float tot  = sred[0] + sred[1];
    const float rinv = 1.0f / sqrtf(tot * (1.0f / (float)C) + EPSV);

    float M[NE * NE];
    #pragma unroll
    for (int k = 0; k < NE * NE; ++k) M[k] = sM[k];

    // ---- outputs, chunk by chunk (w re-read per chunk: 16 KB, L2-hot) ----
    #pragma unroll
    for (int v = 0; v < NV; ++v) {
        const int off = v * (THREADS * 4) + tid * 4;
        float wf[4];
        ld4(w + off, wf);
        float y[4];
        #pragma unroll
        for (int e = 0; e < 4; ++e) {
            float a = s0 * xs[0][v][e] + s1 * xs[1][v][e]
                    + s2 * xs[2][v][e] + s3 * xs[3][v][e];
            y[e] = bf16_rne(a) * rinv * wf[e];
        }
        #pragma unroll
        for (int i = 0; i < NE; ++i) {
            float o[4];
            #pragma unroll
            for (int e = 0; e < 4; ++e)
                o[e] = M[i * NE + 0] * xs[0][v][e] + M[i * NE + 1] * xs[1][v][e]
                     + M[i * NE + 2] * xs[2][v][e] + M[i * NE + 3] * xs[3][v][e]
                     + hp[i] * y[e];
            *reinterpret_cast<float4*>(orow + i * C + off) =
                make_float4(o[0], o[1], o[2], o[3]);
        }
    }
}

extern "C" void kernel_launch(void* const* d_in, const int* in_sizes, int n_in,
                              void* d_out, int out_size, void* d_ws, size_t ws_size,
                              hipStream_t stream) {
    const float* x     = (const float*)d_in[0];
    const float* w     = (const float*)d_in[1];   // f32 on device (np has no bf16)
    const float* Hpre  = (const float*)d_in[2];
    const float* Hpost = (const float*)d_in[3];
    const float* Hres  = (const float*)d_in[4];
    float* out         = (float*)d_out;

    mhc_row<<<B, THREADS, 0, stream>>>(x, w, Hpre, Hpost, Hres, out);
}

// Round 14
// 105.616 us; speedup vs baseline: 1.0405x; 1.0405x over previous
//
#include <hip/hip_runtime.h>

// Problem constants (from reference)
constexpr int C   = 4096;   // HIDDEN_DIM
constexpr int NE  = 4;      // EXPANSION
constexpr int B   = 4096;   // batch rows
constexpr int THREADS = 512;
constexpr int RPB = 8;      // rows per block (pipeline depth)
constexpr float EPSV = 1e-5f;

// Manual RNE round-to-bf16-and-back (value-based)
__device__ inline float bf16_rne(float f) {
    unsigned int u = __float_as_uint(f);
    unsigned int r = (u + 0x7FFFu + ((u >> 16) & 1u)) & 0xFFFF0000u;
    return __uint_as_float(r);
}

__device__ __forceinline__ void ld4(const float* __restrict__ p, float (&d)[4]) {
    float4 t = *reinterpret_cast<const float4*>(p);
    d[0] = t.x; d[1] = t.y; d[2] = t.z; d[3] = t.w;
}
__device__ __forceinline__ void st4(float* __restrict__ p, const float (&d)[4]) {
    *reinterpret_cast<float4*>(p) = make_float4(d[0], d[1], d[2], d[3]);
}

// LDS-only barrier: waits ONLY lgkmcnt(0) (LDS visibility), NOT vmcnt(0).
// __syncthreads() would drain all in-flight global stores/loads (compiler
// emits s_waitcnt vmcnt(0) before s_barrier) — that drain serialized the
// previous step's 32 KB store burst into every step. Stores here are
// thread-disjoint and never re-read, so vmcnt ordering is not needed.
__device__ __forceinline__ void lds_barrier() {
    asm volatile("s_waitcnt lgkmcnt(0)\n\ts_barrier" ::: "memory");
}

// Dense-addressed pipelined kernel, RPB rows per block, double-buffered regs.
// Prefetch of row r+1 issued BEFORE the reduce; it stays in flight across the
// (lgkm-only) barrier. Store stream drains only at kernel end.
__global__ __launch_bounds__(THREADS)
void mhc_pipe(const float* __restrict__ x,
              const float* __restrict__ w,   // rmsnorm_weight stored as f32 on device
              const float* __restrict__ Hpre,
              const float* __restrict__ Hpost,
              const float* __restrict__ Hres,
              float* __restrict__ out) {
    const int tid  = threadIdx.x;
    const int lane = tid & 63;
    const int wid  = tid >> 6;
    const int cA   = wid * 256 + lane * 4;   // dense 1 KB per wave instruction
    const int cB   = 2048 + cA;
    const size_t blockbase = (size_t)blockIdx.x * RPB * NE * C;

    __shared__ float sM[NE * NE];
    __shared__ float red[RPB][THREADS / 64];

    // ---- wave 0: lane-parallel Sinkhorn (butterfly); published at first barrier ----
    if (tid < 64) {
        float m = (tid < 16) ? expf(Hres[tid]) : 0.0f;
        for (int it = 0; it < 20; ++it) {
            float r = m + __shfl_xor(m, 1);
            r += __shfl_xor(r, 2);
            m /= fmaxf(r, EPSV);
            float cs = m + __shfl_xor(m, 4);
            cs += __shfl_xor(cs, 8);
            m /= fmaxf(cs, EPSV);
        }
        if (tid < 16) sM[tid] = m;
    }

    // ---- gates (uniform, cheap, per-thread) ----
    const float s0 = 1.0f / (1.0f + expf(-Hpre[0]));
    const float s1 = 1.0f / (1.0f + expf(-Hpre[1]));
    const float s2 = 1.0f / (1.0f + expf(-Hpre[2]));
    const float s3 = 1.0f / (1.0f + expf(-Hpre[3]));
    float hp[NE];
    #pragma unroll
    for (int i = 0; i < NE; ++i) hp[i] = 2.0f / (1.0f + expf(-Hpost[i]));

    // ---- w slices (fixed per thread; L2-hot) ----
    float wf[2][4];
    ld4(w + cA, wf[0]);
    ld4(w + cB, wf[1]);

    float xsA[NE][2][4], xsB[NE][2][4];
    float M[NE * NE];

    auto load_row = [&](const float* __restrict__ xrow, float (&xs)[NE][2][4]) {
        #pragma unroll
        for (int k = 0; k < NE; ++k) {
            ld4(xrow + k * C + cA, xs[k][0]);
            ld4(xrow + k * C + cB, xs[k][1]);
        }
    };

    auto step = [&](int r, float (&cur)[NE][2][4], float (&nxt)[NE][2][4]) {
        // ---- aggregate + bf16 round + partial sum of squares (consumes cur) ----
        float aggbf[2][4];
        float ss = 0.0f;
        #pragma unroll
        for (int h = 0; h < 2; ++h)
            #pragma unroll
            for (int e = 0; e < 4; ++e) {
                float a = s0 * cur[0][h][e] + s1 * cur[1][h][e]
                        + s2 * cur[2][h][e] + s3 * cur[3][h][e];
                float abf = bf16_rne(a);
                aggbf[h][e] = abf;
                ss += abf * abf;
            }

        // ---- prefetch next row NOW; stays in flight across the lgkm-only barrier ----
        if (r + 1 < RPB)
            load_row(x + blockbase + (size_t)(r + 1) * NE * C, nxt);

        // ---- block reduction (LDS-only barrier; stores/loads NOT drained) ----
        #pragma unroll
        for (int off = 32; off > 0; off >>= 1) ss += __shfl_xor(ss, off);
        if (lane == 0) red[r][wid] = ss;
        lds_barrier();                       // r==0: also publishes sM

        if (r == 0) {
            #pragma unroll
            for (int k = 0; k < NE * NE; ++k) M[k] = sM[k];
        }

        float tot = 0.0f;
        #pragma unroll
        for (int i = 0; i < THREADS / 64; ++i) tot += red[r][i];
        const float rinv = 1.0f / sqrtf(tot * (1.0f / (float)C) + EPSV);

        // ---- outputs (stores drain only at kernel end) ----
        float* orow = out + blockbase + (size_t)r * NE * C;
        float y[2][4];
        #pragma unroll
        for (int h = 0; h < 2; ++h)
            #pragma unroll
            for (int e = 0; e < 4; ++e)
                y[h][e] = aggbf[h][e] * rinv * wf[h][e];

        #pragma unroll
        for (int i = 0; i < NE; ++i) {
            float o[2][4];
            #pragma unroll
            for (int h = 0; h < 2; ++h)
                #pragma unroll
                for (int e = 0; e < 4; ++e)
                    o[h][e] = M[i * NE + 0] * cur[0][h][e] + M[i * NE + 1] * cur[1][h][e]
                            + M[i * NE + 2] * cur[2][h][e] + M[i * NE + 3] * cur[3][h][e]
                            + hp[i] * y[h][e];
            st4(orow + i * C + cA, o[0]);
            st4(orow + i * C + cB, o[1]);
        }
    };

    load_row(x + blockbase, xsA);
    step(0, xsA, xsB);
    step(1, xsB, xsA);
    step(2, xsA, xsB);
    step(3, xsB, xsA);
    step(4, xsA, xsB);
    step(5, xsB, xsA);
    step(6, xsA, xsB);
    step(7, xsB, xsA);
}

extern "C" void kernel_launch(void* const* d_in, const int* in_sizes, int n_in,
                              void* d_out, int out_size, void* d_ws, size_t ws_size,
                              hipStream_t stream) {
    const float* x     = (const float*)d_in[0];
    const float* w     = (const float*)d_in[1];   // f32 on device (np has no bf16)
    const float* Hpre  = (const float*)d_in[2];
    const float* Hpost = (const float*)d_in[3];
    const float* Hres  = (const float*)d_in[4];
    float* out         = (float*)d_out;

    mhc_pipe<<<B / RPB, THREADS, 0, stream>>>(x, w, Hpre, Hpost, Hres, out);
}